// Round 8
// baseline (118.287 us; speedup 1.0000x reference)
//
#include <hip/hip_runtime.h>
#include <hip/hip_bf16.h>

// Problem constants
#define K_DIM 4096
#define N_DIM 14336
#define M_DIM 256
#define BM 128
#define BN 64
#define BK 32
#define PH 128          // K_DIM / BK phases
#define NG 32           // quant groups

typedef __attribute__((ext_vector_type(4))) float f32x4;
typedef __attribute__((ext_vector_type(8))) short short8;

__device__ __forceinline__ unsigned short f2bf(float f) {
    union { float f; unsigned u; } v; v.f = f;
    unsigned r = v.u + 0x7fffu + ((v.u >> 16) & 1u);   // RNE
    return (unsigned short)(r >> 16);
}

__device__ __forceinline__ void glds16(const void* g, void* l) {
    __builtin_amdgcn_global_load_lds(
        (const __attribute__((address_space(1))) void*)g,
        (__attribute__((address_space(3))) void*)l, 16, 0, 0);
}

// LDS visibility + counted vmem drain; prefetch stays in flight (T4).
#define KBAR(N) do { \
    asm volatile("s_waitcnt lgkmcnt(0)" ::: "memory");     \
    asm volatile("s_waitcnt vmcnt(" #N ")" ::: "memory");  \
    __builtin_amdgcn_s_barrier();                           \
} while (0)

// x (fp32 [256][4096]) -> bf16 MFMA-A-fragment order. chunk = ktile*16+mtile;
// lane l holds x[mtile*16+(l&15)][ktile*32+(l>>4)*8 ..+8]  (1 KB per chunk)
__global__ void convert_x_kernel(const float* __restrict__ x,
                                 unsigned short* __restrict__ xf) {
    int t = blockIdx.x * blockDim.x + threadIdx.x;   // 0..131071
    int chunk = t >> 6;
    int lane  = t & 63;
    int ktile = chunk >> 4;
    int mtile = chunk & 15;
    int m = mtile * 16 + (lane & 15);
    int k = ktile * 32 + ((lane >> 4) << 3);
    const float* xp = x + (size_t)m * K_DIM + k;
    float4 lo = *(const float4*)xp;
    float4 hi = *(const float4*)(xp + 4);
    union { unsigned short s[8]; int4 v; } o;
    o.s[0] = f2bf(lo.x); o.s[1] = f2bf(lo.y); o.s[2] = f2bf(lo.z); o.s[3] = f2bf(lo.w);
    o.s[4] = f2bf(hi.x); o.s[5] = f2bf(hi.y); o.s[6] = f2bf(hi.z); o.s[7] = f2bf(hi.w);
    *(int4*)(xf + ((size_t)t << 3)) = o.v;
}

// xg[m][g] = sum_{k in group g} x[m][k], bf16. Grid 256 x 128 threads.
__global__ void xg_kernel(const float* __restrict__ x,
                          unsigned short* __restrict__ xg) {
    __shared__ float part[128];
    const int m = blockIdx.x, t = threadIdx.x;
    const float* xp = x + (size_t)m * K_DIM + t * 32;
    float s = 0.f;
    #pragma unroll
    for (int j = 0; j < 32; j += 4) {
        float4 v = *(const float4*)(xp + j);
        s += v.x + v.y + v.z + v.w;
    }
    part[t] = s;
    __syncthreads();
    if (t < NG) {
        float g = part[4*t] + part[4*t+1] + part[4*t+2] + part[4*t+3];
        xg[(size_t)m * NG + t] = f2bf(g);
    }
}

// v10: 448 blocks x 512 thr (8 waves = 4m x 2n), 72 KB LDS -> 2 blocks/CU,
// ALL blocks resident. 4-slot glds pipeline (q raw + A), KBAR(4) = 2-phase
// forced slack. MFMA on RAW q (exact in bf16); scale applied per group into
// acc; zero-point via analytic xg.z rank-32 MFMA in epilogue. No dequant
// pass, no LDS writes in the main loop.
__global__ __launch_bounds__(512, 4)
void plq_gemm_v10(const unsigned short* __restrict__ xf,
                  const unsigned short* __restrict__ xg,
                  const int* __restrict__ q,
                  const float* __restrict__ qs,
                  const float* __restrict__ qb,
                  const float* __restrict__ bias,
                  float* __restrict__ out)
{
    __shared__ int            qt[4][BK * BN];   // 4 x 8 KB raw q [k][n]
    __shared__ unsigned short at[4][BM * BK];   // 4 x 8 KB A fragments
    __shared__ float          sl[NG * BN];      // 8 KB scales [g][n]

    const int tid  = threadIdx.x;
    const int lane = tid & 63;
    const int wv   = tid >> 6;          // 0..7
    const int wm   = wv >> 1;           // 0..3 (32 m-rows each)
    const int wn   = wv & 1;            // 0..1 (32 n-cols each)
    const int l4   = lane >> 4;         // 0..3
    const int lc   = lane & 15;

    // XCD-chunked remap (448 = 8*56): m-half twins adjacent -> q L2 reuse
    const int gid = (blockIdx.x & 7) * 56 + (blockIdx.x >> 3);
    const int mh  = gid & 1;
    const int n0  = (gid >> 1) * BN;

    const f32x4 vzero = {0.f, 0.f, 0.f, 0.f};
    f32x4 acc[2][2] = {}, gacc[2][2] = {};

    auto issueT = [&](int t) {          // 2 glds per wave, uniform
        const int* qsrc = q + (size_t)(t * BK + 4 * wv + l4) * N_DIM + n0 + lc * 4;
        glds16(qsrc, (char*)&qt[t & 3][0] + (wv << 10));
        const unsigned short* asrc = xf + ((size_t)(t * 16 + mh * 8 + wv) << 9) + (lane << 3);
        glds16(asrc, (char*)&at[t & 3][0] + (wv << 10));
    };

    auto compute = [&](int slot) {
        short8 a0 = *(const short8*)&at[slot][(wm * 2 + 0) * 512 + (lane << 3)];
        short8 a1 = *(const short8*)&at[slot][(wm * 2 + 1) * 512 + (lane << 3)];
        #pragma unroll
        for (int nf = 0; nf < 2; ++nf) {
            const int cb = wn * 32 + nf * 16 + lc;
            unsigned u[8];
            #pragma unroll
            for (int j = 0; j < 8; ++j) {
                float fv = (float)qt[slot][(l4 * 8 + j) * BN + cb];  // exact
                union { float f; unsigned w; } cv; cv.f = fv;
                u[j] = cv.w;
            }
            union { unsigned w[4]; short8 s; } b;
            b.w[0] = __builtin_amdgcn_perm(u[1], u[0], 0x07060302u); // hi16 pair
            b.w[1] = __builtin_amdgcn_perm(u[3], u[2], 0x07060302u);
            b.w[2] = __builtin_amdgcn_perm(u[5], u[4], 0x07060302u);
            b.w[3] = __builtin_amdgcn_perm(u[7], u[6], 0x07060302u);
            gacc[0][nf] = __builtin_amdgcn_mfma_f32_16x16x32_bf16(a0, b.s, gacc[0][nf], 0, 0, 0);
            gacc[1][nf] = __builtin_amdgcn_mfma_f32_16x16x32_bf16(a1, b.s, gacc[1][nf], 0, 0, 0);
        }
    };

    auto applyS = [&](int g) {
        #pragma unroll
        for (int nf = 0; nf < 2; ++nf) {
            float s = sl[g * BN + wn * 32 + nf * 16 + lc];
            #pragma unroll
            for (int mf = 0; mf < 2; ++mf) {
                acc[mf][nf] += gacc[mf][nf] * s;
                gacc[mf][nf] = vzero;
            }
        }
    };

    // ---- prologue ----
    #pragma unroll
    for (int j = 0; j < 4; ++j) {       // scales -> LDS
        int idx = tid + j * 512;        // [g 0..31][n 0..63]
        sl[idx] = qs[(size_t)(idx >> 6) * N_DIM + n0 + (idx & 63)];
    }
    issueT(0); issueT(1); issueT(2);    // 6 glds
    KBAR(4);                            // tile0 + sl complete; t1,t2 flying

    // ---- main loop: groups 0..30, 4 phases each, slot = phase & 3 ----
    #pragma unroll 1
    for (int g = 0; g < 31; ++g) {
        const int p = g * 4;
        issueT(p + 3); compute(0); KBAR(4);
        issueT(p + 4); compute(1); KBAR(4);
        issueT(p + 5); compute(2); KBAR(4);
        issueT(p + 6); compute(3); KBAR(4);
        applyS(g);
    }
    // ---- group 31: phases 124..127 ----
    issueT(127); compute(0); KBAR(4);
    compute(1); KBAR(2);
    compute(2); KBAR(0);
    compute(3);
    applyS(31);

    // ---- zero-point term: acc += xg . z  (rank-32, one k=32 MFMA) ----
    {
        short8 xa0 = *(const short8*)(xg + (size_t)(mh * 128 + wm * 32 + 0 * 16 + lc) * NG + l4 * 8);
        short8 xa1 = *(const short8*)(xg + (size_t)(mh * 128 + wm * 32 + 1 * 16 + lc) * NG + l4 * 8);
        #pragma unroll
        for (int nf = 0; nf < 2; ++nf) {
            const int n = n0 + wn * 32 + nf * 16 + lc;
            union { unsigned w[4]; short8 s; } b;
            #pragma unroll
            for (int j = 0; j < 4; ++j) {
                float z0 = qb[(size_t)(l4 * 8 + 2 * j)     * N_DIM + n];
                float z1 = qb[(size_t)(l4 * 8 + 2 * j + 1) * N_DIM + n];
                b.w[j] = (unsigned)f2bf(z0) | ((unsigned)f2bf(z1) << 16);
            }
            acc[0][nf] = __builtin_amdgcn_mfma_f32_16x16x32_bf16(xa0, b.s, acc[0][nf], 0, 0, 0);
            acc[1][nf] = __builtin_amdgcn_mfma_f32_16x16x32_bf16(xa1, b.s, acc[1][nf], 0, 0, 0);
        }
    }

    // ---- epilogue: C/D col = lane&15, row = (lane>>4)*4 + r ----
    #pragma unroll
    for (int nf = 0; nf < 2; ++nf) {
        const int n = n0 + wn * 32 + nf * 16 + lc;
        const float bv = bias[n];
        #pragma unroll
        for (int mf = 0; mf < 2; ++mf) {
            const int m0 = mh * 128 + wm * 32 + mf * 16 + l4 * 4;
            #pragma unroll
            for (int r = 0; r < 4; ++r)
                out[(size_t)(m0 + r) * N_DIM + n] = acc[mf][nf][r] + bv;
        }
    }
}

// ---------------- fallback (no workspace): round-1 structure ----
#define FBN 64
#define FBK 128
#define FNITER 32
#define FRS 136
__global__ __launch_bounds__(512, 2)
void plq_gemm_fb(const float* __restrict__ x,
                 const int* __restrict__ q,
                 const float* __restrict__ qs,
                 const float* __restrict__ qb,
                 const float* __restrict__ bias,
                 float* __restrict__ out)
{
    __shared__ unsigned short wlds[2][FBN * FRS];
    const int tid  = threadIdx.x;
    const int lane = tid & 63;
    const int wv   = tid >> 6;
    const int wm   = wv >> 1;
    const int wn   = wv & 1;
    const int n0   = blockIdx.x * FBN;
    const int nl = (tid & 31) * 2;
    const int kl = (tid >> 5) * 8;

    f32x4 acc[4][2] = {};
    int2   qr[8];
    float2 sv, zv;

    auto loadq = [&](int i) {
        const int* qp = q + (size_t)(i * FBK + kl) * N_DIM + (n0 + nl);
        #pragma unroll
        for (int j = 0; j < 8; ++j) qr[j] = *(const int2*)(qp + (size_t)j * N_DIM);
        sv = *(const float2*)(qs + (size_t)i * N_DIM + (n0 + nl));
        zv = *(const float2*)(qb + (size_t)i * N_DIM + (n0 + nl));
    };
    auto deqw = [&](int b) {
        union { unsigned u[4]; int4 v; } p0, p1;
        #pragma unroll
        for (int j = 0; j < 4; ++j) {
            float a0 = (float)qr[2*j].x   * sv.x + zv.x;
            float a1 = (float)qr[2*j+1].x * sv.x + zv.x;
            float c0 = (float)qr[2*j].y   * sv.y + zv.y;
            float c1 = (float)qr[2*j+1].y * sv.y + zv.y;
            p0.u[j] = (unsigned)f2bf(a0) | ((unsigned)f2bf(a1) << 16);
            p1.u[j] = (unsigned)f2bf(c0) | ((unsigned)f2bf(c1) << 16);
        }
        *(int4*)&wlds[b][(nl + 0) * FRS + kl] = p0.v;
        *(int4*)&wlds[b][(nl + 1) * FRS + kl] = p1.v;
    };
    auto compute = [&](int i, int cur) {
        short8 afr[4][4];
        #pragma unroll
        for (int ks = 0; ks < 4; ++ks)
            #pragma unroll
            for (int mf = 0; mf < 4; ++mf) {
                int m = wm * 64 + mf * 16 + (lane & 15);
                int k = i * FBK + ks * 32 + ((lane >> 4) << 3);
                const float* xp = x + (size_t)m * K_DIM + k;
                float4 lo = *(const float4*)xp;
                float4 hi = *(const float4*)(xp + 4);
                union { unsigned short s[8]; short8 v; } u;
                u.s[0] = f2bf(lo.x); u.s[1] = f2bf(lo.y); u.s[2] = f2bf(lo.z); u.s[3] = f2bf(lo.w);
                u.s[4] = f2bf(hi.x); u.s[5] = f2bf(hi.y); u.s[6] = f2bf(hi.z); u.s[7] = f2bf(hi.w);
                afr[ks][mf] = u.v;
            }
        #pragma unroll
        for (int ks = 0; ks < 4; ++ks) {
            const int kb = ks * 32 + ((lane >> 4) << 3);
            short8 b0 = *(const short8*)&wlds[cur][(wn * 32 +      (lane & 15)) * FRS + kb];
            short8 b1 = *(const short8*)&wlds[cur][(wn * 32 + 16 + (lane & 15)) * FRS + kb];
            #pragma unroll
            for (int mf = 0; mf < 4; ++mf) {
                acc[mf][0] = __builtin_amdgcn_mfma_f32_16x16x32_bf16(afr[ks][mf], b0, acc[mf][0], 0, 0, 0);
                acc[mf][1] = __builtin_amdgcn_mfma_f32_16x16x32_bf16(afr[ks][mf], b1, acc[mf][1], 0, 0, 0);
            }
        }
    };

    loadq(0); deqw(0); __syncthreads();
    for (int i = 0; i < FNITER; ++i) {
        const int cur = i & 1;
        if (i + 1 < FNITER) loadq(i + 1);
        compute(i, cur);
        if (i + 1 < FNITER) deqw(cur ^ 1);
        __syncthreads();
    }
    #pragma unroll
    for (int nf = 0; nf < 2; ++nf) {
        const int n = n0 + wn * 32 + nf * 16 + (lane & 15);
        const float bb = bias[n];
        #pragma unroll
        for (int mf = 0; mf < 4; ++mf) {
            const int m0 = wm * 64 + mf * 16 + ((lane >> 4) << 2);
            #pragma unroll
            for (int r = 0; r < 4; ++r)
                out[(size_t)(m0 + r) * N_DIM + n] = acc[mf][nf][r] + bb;
        }
    }
}

extern "C" void kernel_launch(void* const* d_in, const int* in_sizes, int n_in,
                              void* d_out, int out_size, void* d_ws, size_t ws_size,
                              hipStream_t stream) {
    const float* x    = (const float*)d_in[0];
    const int*   qk   = (const int*)d_in[1];
    const float* qs   = (const float*)d_in[2];
    const float* qb   = (const float*)d_in[3];
    const float* bias = (const float*)d_in[4];
    float* out = (float*)d_out;

    const size_t xf_bytes = (size_t)M_DIM * K_DIM * sizeof(unsigned short);   // 2 MB
    const size_t xg_bytes = (size_t)M_DIM * NG * sizeof(unsigned short);      // 16 KB
    if (ws_size >= xf_bytes + xg_bytes) {
        unsigned short* xf = (unsigned short*)d_ws;
        unsigned short* xg = (unsigned short*)((char*)d_ws + xf_bytes);
        convert_x_kernel<<<512, 256, 0, stream>>>(x, xf);
        xg_kernel<<<M_DIM, 128, 0, stream>>>(x, xg);
        const int grid = (M_DIM / BM) * (N_DIM / BN);   // 2 * 224 = 448
        plq_gemm_v10<<<grid, 512, 0, stream>>>(xf, xg, qk, qs, qb, bias, out);
    } else {
        plq_gemm_fb<<<N_DIM / FBN, 512, 0, stream>>>(x, qk, qs, qb, bias, out);
    }
}